// Round 5
// baseline (523.007 us; speedup 1.0000x reference)
//
#include <hip/hip_runtime.h>
#include <hip/hip_bf16.h>

#define N_NODES 50000
#define N_EDGES 800000
#define N_GRAPHS 1024
#define D_IN 64
#define D_PROT 1280
#define HID 256
#define GPB 4
#define N_PAD 50048   // N_NODES padded to multiple of 64

// edge bucketing: 64 nodes per bucket
#define NB 782        // ceil(50048/64)
#define BCAP 2048     // capacity per bucket (mean 1023, max ~1200)
#define EPB 8192      // edges per k_bucket block
#define NABLK 98      // ceil(800000/8192)

typedef __attribute__((ext_vector_type(8))) short short8;
typedef __attribute__((ext_vector_type(4))) float f32x4;
typedef __hip_bfloat16 bf16;

// round-to-nearest-even f32 -> bf16 bits (finite inputs only)
__device__ inline unsigned bf16rne(float f) {
  unsigned u = __float_as_uint(f);
  return (u + 0x7fffu + ((u >> 16) & 1u)) >> 16;
}

// ---------------------------------------------------------------------------
// k_prep: fused conversions + weight packing (histogram no longer needed).
// ---------------------------------------------------------------------------
#define PREP_XC 3125                  // 50000*64/4 float4s / 256
#define PREP_PE (PREP_XC + 1280)      // 1024*1280/4 / 256
#define PREP_PL (PREP_PE + 8)         // 16 coltiles * 2 kc * 64 lanes / 256
#define PREP_PR (PREP_PL + 8)
#define PREP_PP (PREP_PR + 160)       // 16 * 40 * 64 / 256

__device__ inline void pack_frag(const float* __restrict__ src, bf16* __restrict__ dst,
                                 int KC, int tid) {
  int lane = tid & 63;
  int chunk = tid >> 6;            // = c*KC + kc
  int c = chunk / KC, kc = chunk - c * KC;
  int kbase = kc * 32 + ((lane >> 4) * 8);
  int n = c * 16 + (lane & 15);
#pragma unroll
  for (int j = 0; j < 8; ++j)
    dst[(size_t)tid * 8 + j] = __float2bfloat16(src[(size_t)(kbase + j) * HID + n]);
}

__global__ __launch_bounds__(256) void k_prep(
    const float* __restrict__ x, const float* __restrict__ pe,
    const float* __restrict__ Wl, const float* __restrict__ Wr,
    const float* __restrict__ Wp,
    uint2* __restrict__ x2, uint2* __restrict__ pe2,
    bf16* __restrict__ Wl_pk, bf16* __restrict__ Wr_pk, bf16* __restrict__ Wp_pk) {
  int b = blockIdx.x;
  if (b < PREP_XC) {
    int tid = b * 256 + threadIdx.x;
    float4 v = ((const float4*)x)[tid];
    x2[tid] = make_uint2(bf16rne(v.x) | (bf16rne(v.y) << 16),
                         bf16rne(v.z) | (bf16rne(v.w) << 16));
  } else if (b < PREP_PE) {
    int tid = (b - PREP_XC) * 256 + threadIdx.x;
    float4 v = ((const float4*)pe)[tid];
    pe2[tid] = make_uint2(bf16rne(v.x) | (bf16rne(v.y) << 16),
                          bf16rne(v.z) | (bf16rne(v.w) << 16));
  } else if (b < PREP_PL) {
    pack_frag(Wl, Wl_pk, 2, (b - PREP_PE) * 256 + threadIdx.x);
  } else if (b < PREP_PR) {
    pack_frag(Wr, Wr_pk, 2, (b - PREP_PL) * 256 + threadIdx.x);
  } else {
    pack_frag(Wp, Wp_pk, 40, (b - PREP_PR) * 256 + threadIdx.x);
  }
}

// ---------------------------------------------------------------------------
// k_bucket: bin edges into NB coarse buckets (dst>>6), packed src|(dst&63)<<16.
// Per-block LDS histogram + ONE global reservation per (block,bucket) so each
// bucket receives a contiguous run from this block (line-merged writes).
// ---------------------------------------------------------------------------
__global__ __launch_bounds__(256) void k_bucket(
    const int* __restrict__ ei, int* __restrict__ bcnt,
    unsigned* __restrict__ bped) {
  __shared__ int hist[NB];
  __shared__ int base[NB];
  const int t = threadIdx.x;
  const int e0 = blockIdx.x * EPB;
  for (int i = t; i < NB; i += 256) hist[i] = 0;
  __syncthreads();
  for (int i = t; i < EPB; i += 256) {
    int e = e0 + i;
    if (e < N_EDGES) atomicAdd(&hist[ei[N_EDGES + e] >> 6], 1);
  }
  __syncthreads();
  for (int i = t; i < NB; i += 256) {
    int c = hist[i];
    base[i] = (c > 0) ? atomicAdd(&bcnt[i], c) : 0;
    hist[i] = 0;  // reuse as local cursor
  }
  __syncthreads();
  for (int i = t; i < EPB; i += 256) {
    int e = e0 + i;
    if (e < N_EDGES) {
      int src = ei[e], dst = ei[N_EDGES + e];
      int bk = dst >> 6;
      int pos = base[bk] + atomicAdd(&hist[bk], 1);
      if (pos < BCAP)
        bped[(size_t)bk * BCAP + pos] = (unsigned)src | ((unsigned)(dst & 63) << 16);
    }
  }
}

// ---------------------------------------------------------------------------
// k_aggr: one block per bucket. Gather x rows of this bucket's edges
// (16 lanes x uint2 per row, 4 edges/wave-group, 4-deep ILP), accumulate
// fp32 in LDS via ds_add (stride 66 floats: <=2-way bank aliasing), then
// write the bf16 mean row. Replaces CSR fill/scan/gather entirely.
// ---------------------------------------------------------------------------
__global__ __launch_bounds__(256) void k_aggr(
    const uint2* __restrict__ x2, const unsigned* __restrict__ bped,
    const int* __restrict__ bcnt, uint2* __restrict__ a2) {
  __shared__ float accum[64 * 66];   // 16.5 KB
  __shared__ int ldeg[64];
  const int t = threadIdx.x;
  const int b = blockIdx.x;
  const int nE = min(bcnt[b], BCAP);
  for (int i = t; i < 64 * 66; i += 256) accum[i] = 0.f;
  if (t < 64) ldeg[t] = 0;
  __syncthreads();

  const int el = (t >> 4) & 3;   // edge slot (4 edges per wave step)
  const int fb = t & 15;         // uint2 feature block
  const int w = t >> 6;
  const unsigned* bp = bped + (size_t)b * BCAP;

  for (int e0 = w * 4; e0 < nE; e0 += 64) {   // 4-deep: slots at +0,+16,+32,+48
    int eidx[4];
    unsigned pk[4];
    uint2 xv[4];
    bool vld[4];
#pragma unroll
    for (int u = 0; u < 4; ++u) {
      eidx[u] = e0 + u * 16 + el;
      vld[u] = eidx[u] < nE;
      pk[u] = vld[u] ? bp[eidx[u]] : 0u;
    }
#pragma unroll
    for (int u = 0; u < 4; ++u)
      xv[u] = vld[u] ? x2[(size_t)(pk[u] & 0xffffu) * 16 + fb] : make_uint2(0u, 0u);
#pragma unroll
    for (int u = 0; u < 4; ++u) {
      if (vld[u]) {
        int ld = pk[u] >> 16;
        float* row = accum + ld * 66 + fb * 4;
        atomicAdd(row + 0, __uint_as_float(xv[u].x << 16));
        atomicAdd(row + 1, __uint_as_float(xv[u].x & 0xffff0000u));
        atomicAdd(row + 2, __uint_as_float(xv[u].y << 16));
        atomicAdd(row + 3, __uint_as_float(xv[u].y & 0xffff0000u));
        if (fb == 0) atomicAdd(&ldeg[ld], 1);
      }
    }
  }
  __syncthreads();

  // mean + pack + store (1024 uint2 per block)
  for (int i = t; i < 64 * 16; i += 256) {
    int ld = i >> 4, f4 = i & 15;
    int node = b * 64 + ld;
    if (node < N_NODES) {
      float inv = 1.0f / (float)max(ldeg[ld], 1);
      const float* row = accum + ld * 66 + f4 * 4;
      uint2 o;
      o.x = bf16rne(row[0] * inv) | (bf16rne(row[1] * inv) << 16);
      o.y = bf16rne(row[2] * inv) | (bf16rne(row[3] * inv) << 16);
      a2[(size_t)node * 16 + f4] = o;
    }
  }
}

// ---------------------------------------------------------------------------
// k_mlp: pure MFMA GEMM [64 rows x 128] @ [128 x 256] + bias + relu ->
// drug (bf16). No LDS, no atomics, no divergent branches.
// ---------------------------------------------------------------------------
__global__ __launch_bounds__(256) void k_mlp(
    const bf16* __restrict__ aggrbf, const bf16* __restrict__ xbf,
    const bf16* __restrict__ Wl_pk, const bf16* __restrict__ Wr_pk,
    const float* __restrict__ bl, unsigned short* __restrict__ drug) {
  const int t = threadIdx.x, w = t >> 6, lane = t & 63;
  const int ml = lane & 15, q = lane >> 4;
  const int n0 = blockIdx.x * 64;

  f32x4 acc[4][4];
#pragma unroll
  for (int a = 0; a < 4; ++a)
#pragma unroll
    for (int c = 0; c < 4; ++c) acc[a][c] = (f32x4){0.f, 0.f, 0.f, 0.f};

#pragma unroll
  for (int mat = 0; mat < 2; ++mat) {
    const bf16* A = mat ? xbf : aggrbf;
    const bf16* B = mat ? Wr_pk : Wl_pk;
#pragma unroll
    for (int kc = 0; kc < 2; ++kc) {
      short8 af[4], bfr[4];
#pragma unroll
      for (int rt = 0; rt < 4; ++rt)
        af[rt] = *(const short8*)(A + (size_t)(n0 + rt * 16 + ml) * D_IN + kc * 32 + q * 8);
#pragma unroll
      for (int cl = 0; cl < 4; ++cl)
        bfr[cl] = *(const short8*)(B + ((size_t)((w * 4 + cl) * 2 + kc) * 64 + lane) * 8);
#pragma unroll
      for (int rt = 0; rt < 4; ++rt)
#pragma unroll
        for (int cl = 0; cl < 4; ++cl)
          acc[rt][cl] = __builtin_amdgcn_mfma_f32_16x16x32_bf16(af[rt], bfr[cl], acc[rt][cl], 0, 0, 0);
    }
  }

#pragma unroll
  for (int cl = 0; cl < 4; ++cl) {
    const int col = w * 64 + cl * 16 + ml;
    const float bias = bl[col];
#pragma unroll
    for (int rt = 0; rt < 4; ++rt) {
#pragma unroll
      for (int i = 0; i < 4; ++i) {
        const int row = n0 + rt * 16 + q * 4 + i;
        drug[(size_t)row * HID + col] =
            (unsigned short)bf16rne(fmaxf(acc[rt][cl][i] + bias, 0.f));
      }
    }
  }
}

// ---------------------------------------------------------------------------
// k_pool: one block per graph; binary search sorted batch for row range,
// column-sum drug rows (coalesced), write mean. Zero atomics.
// ---------------------------------------------------------------------------
__device__ inline int lb_dev(const int* __restrict__ a, int v) {
  int lo = 0, hi = N_NODES;
  while (lo < hi) { int m = (lo + hi) >> 1; if (a[m] < v) lo = m + 1; else hi = m; }
  return lo;
}

__global__ __launch_bounds__(256) void k_pool(
    const unsigned short* __restrict__ drug, const int* __restrict__ batch,
    float* __restrict__ pooled) {
  const int g = blockIdx.x, t = threadIdx.x;
  const int lo = lb_dev(batch, g);
  const int hi = lb_dev(batch, g + 1);
  float s0 = 0.f, s1 = 0.f, s2 = 0.f, s3 = 0.f;
  int r = lo;
  for (; r + 4 <= hi; r += 4) {
    s0 += __uint_as_float((unsigned)drug[(size_t)(r + 0) * HID + t] << 16);
    s1 += __uint_as_float((unsigned)drug[(size_t)(r + 1) * HID + t] << 16);
    s2 += __uint_as_float((unsigned)drug[(size_t)(r + 2) * HID + t] << 16);
    s3 += __uint_as_float((unsigned)drug[(size_t)(r + 3) * HID + t] << 16);
  }
  for (; r < hi; ++r)
    s0 += __uint_as_float((unsigned)drug[(size_t)r * HID + t] << 16);
  float inv = 1.0f / (float)max(hi - lo, 1);
  pooled[(size_t)g * HID + t] = ((s0 + s1) + (s2 + s3)) * inv;
}

// ---------------------------------------------------------------------------
// k_prot: pe[1024x1280] @ Wp[1280x256], K-split x4 -> prot4 partial slices.
// ---------------------------------------------------------------------------
__global__ __launch_bounds__(256) void k_prot(
    const bf16* __restrict__ pebf, const bf16* __restrict__ Wp_pk,
    float* __restrict__ prot4) {
  const int w = threadIdx.x >> 6, lane = threadIdx.x & 63;
  const int ml = lane & 15, q = lane >> 4;
  const int mt = blockIdx.x >> 2, ks = blockIdx.x & 3;
  const int g0 = mt * 16, kc0 = ks * 10;
  f32x4 acc[4];
#pragma unroll
  for (int c = 0; c < 4; ++c) acc[c] = (f32x4){0.f, 0.f, 0.f, 0.f};
  for (int kc = kc0; kc < kc0 + 10; ++kc) {
    short8 a = *(const short8*)(pebf + (size_t)(g0 + ml) * D_PROT + kc * 32 + q * 8);
#pragma unroll
    for (int cl = 0; cl < 4; ++cl) {
      short8 b = *(const short8*)(Wp_pk + ((size_t)((w * 4 + cl) * 40 + kc) * 64 + lane) * 8);
      acc[cl] = __builtin_amdgcn_mfma_f32_16x16x32_bf16(a, b, acc[cl], 0, 0, 0);
    }
  }
#pragma unroll
  for (int cl = 0; cl < 4; ++cl) {
    const int col = w * 64 + cl * 16 + ml;
#pragma unroll
    for (int i = 0; i < 4; ++i)
      prot4[((size_t)ks * N_GRAPHS + g0 + q * 4 + i) * HID + col] = acc[cl][i];
  }
}

// ---------------------------------------------------------------------------
// k_tail: combined = [pooled | sum(prot4)+bp]; inter = relu(@Wi+bi);
// out = inter@Wo + bo. Wave-shuffle head reduction.
// ---------------------------------------------------------------------------
__global__ __launch_bounds__(256) void k_tail(
    const float* __restrict__ pooled, const float* __restrict__ prot4,
    const float* __restrict__ bp,
    const float* __restrict__ Wi, const float* __restrict__ bi,
    const float* __restrict__ Wo, const float* __restrict__ bo,
    float* __restrict__ out) {
  __shared__ float sComb[GPB * 2 * HID];
  __shared__ float sRed[4 * GPB];
  const int t = threadIdx.x, w = t >> 6, lane = t & 63;
  const int g0 = blockIdx.x * GPB;

  for (int g = 0; g < GPB; ++g) {
    size_t idx = (size_t)(g0 + g) * HID + t;
    sComb[g * 2 * HID + t] = pooled[idx];
    float pr = prot4[idx] + prot4[(size_t)N_GRAPHS * HID + idx]
             + prot4[2 * (size_t)N_GRAPHS * HID + idx]
             + prot4[3 * (size_t)N_GRAPHS * HID + idx];
    sComb[g * 2 * HID + HID + t] = pr + bp[t];
  }
  __syncthreads();

  float acci[GPB];
  const float bit = bi[t];
#pragma unroll
  for (int g = 0; g < GPB; ++g) acci[g] = bit;
  for (int j = 0; j < 2 * HID; ++j) {
    float wv = Wi[j * HID + t];
#pragma unroll
    for (int g = 0; g < GPB; ++g) acci[g] = fmaf(sComb[g * 2 * HID + j], wv, acci[g]);
  }

  const float wo = Wo[t];
  float p[GPB];
#pragma unroll
  for (int g = 0; g < GPB; ++g) p[g] = fmaxf(acci[g], 0.f) * wo;
#pragma unroll
  for (int off = 32; off > 0; off >>= 1)
#pragma unroll
    for (int g = 0; g < GPB; ++g) p[g] += __shfl_down(p[g], off);
  if (lane == 0)
    for (int g = 0; g < GPB; ++g) sRed[w * GPB + g] = p[g];
  __syncthreads();
  if (t < GPB)
    out[g0 + t] = sRed[0 * GPB + t] + sRed[1 * GPB + t] + sRed[2 * GPB + t]
                + sRed[3 * GPB + t] + bo[0];
}

extern "C" void kernel_launch(void* const* d_in, const int* in_sizes, int n_in,
                              void* d_out, int out_size, void* d_ws, size_t ws_size,
                              hipStream_t stream) {
  const float* x     = (const float*)d_in[0];
  const float* pe    = (const float*)d_in[1];
  const float* Wl    = (const float*)d_in[2];
  const float* bl    = (const float*)d_in[3];
  const float* Wr    = (const float*)d_in[4];
  const float* Wp    = (const float*)d_in[5];
  const float* bp    = (const float*)d_in[6];
  const float* Wi    = (const float*)d_in[7];
  const float* bi    = (const float*)d_in[8];
  const float* Wo    = (const float*)d_in[9];
  const float* bo    = (const float*)d_in[10];
  const int*   ei    = (const int*)d_in[11];
  const int*   batch = (const int*)d_in[12];
  float* out = (float*)d_out;

  char* p = (char*)d_ws;
  auto alloc = [&](size_t bytes) {
    char* r = p;
    p += (bytes + 255) & ~(size_t)255;
    return r;
  };
  int*      bcnt  = (int*)alloc(NB * 4);
  size_t zbytes = (size_t)(p - (char*)d_ws);     // only bcnt needs zeroing
  unsigned* bped  = (unsigned*)alloc((size_t)NB * BCAP * 4);
  bf16*  xbf    = (bf16*)alloc((size_t)N_PAD * D_IN * 2);
  bf16*  aggrbf = (bf16*)alloc((size_t)N_PAD * D_IN * 2);
  bf16*  pebf   = (bf16*)alloc((size_t)N_GRAPHS * D_PROT * 2);
  bf16*  Wl_pk  = (bf16*)alloc((size_t)D_IN * HID * 2);
  bf16*  Wr_pk  = (bf16*)alloc((size_t)D_IN * HID * 2);
  bf16*  Wp_pk  = (bf16*)alloc((size_t)D_PROT * HID * 2);
  float* prot4  = (float*)alloc((size_t)4 * N_GRAPHS * HID * 4);
  unsigned short* drug = (unsigned short*)alloc((size_t)N_PAD * HID * 2);
  float* pooled = (float*)alloc((size_t)N_GRAPHS * HID * 4);

  hipMemsetAsync(d_ws, 0, zbytes, stream);

  k_prep<<<PREP_PP, 256, 0, stream>>>(x, pe, Wl, Wr, Wp,
                                      (uint2*)xbf, (uint2*)pebf,
                                      Wl_pk, Wr_pk, Wp_pk);
  k_bucket<<<NABLK, 256, 0, stream>>>(ei, bcnt, bped);
  k_aggr<<<NB, 256, 0, stream>>>((const uint2*)xbf, bped, bcnt, (uint2*)aggrbf);
  k_prot<<<256, 256, 0, stream>>>(pebf, Wp_pk, prot4);
  k_mlp<<<N_PAD / 64, 256, 0, stream>>>(aggrbf, xbf, Wl_pk, Wr_pk, bl, drug);
  k_pool<<<N_GRAPHS, 256, 0, stream>>>(drug, batch, pooled);
  k_tail<<<N_GRAPHS / GPB, 256, 0, stream>>>(pooled, prot4, bp,
                                             Wi, bi, Wo, bo, out);
}

// Round 6
// 212.509 us; speedup vs baseline: 2.4611x; 2.4611x over previous
//
#include <hip/hip_runtime.h>
#include <hip/hip_bf16.h>

#define N_NODES 50000
#define N_EDGES 800000
#define N_GRAPHS 1024
#define D_IN 64
#define D_PROT 1280
#define HID 256
#define GPB 4
#define N_PAD 50048   // N_NODES padded to multiple of 64

// edge bucketing: 64 nodes per bucket
#define NB 782        // ceil(50048/64)
#define BCAP 2048     // capacity per bucket (mean 1023, max ~1200)
#define EPB 8192      // edges per k_bucket block
#define NABLK 98      // ceil(800000/8192)

typedef __attribute__((ext_vector_type(8))) short short8;
typedef __attribute__((ext_vector_type(4))) float f32x4;
typedef __hip_bfloat16 bf16;

// round-to-nearest-even f32 -> bf16 bits (finite inputs only)
__device__ inline unsigned bf16rne(float f) {
  unsigned u = __float_as_uint(f);
  return (u + 0x7fffu + ((u >> 16) & 1u)) >> 16;
}
// accumulate 4 bf16 packed in uint2 into float4
__device__ inline void acc_bf2(float4& a, uint2 v) {
  a.x += __uint_as_float(v.x << 16);
  a.y += __uint_as_float(v.x & 0xffff0000u);
  a.z += __uint_as_float(v.y << 16);
  a.w += __uint_as_float(v.y & 0xffff0000u);
}

// ---------------------------------------------------------------------------
// k_prep: fused conversions + weight packing.
// ---------------------------------------------------------------------------
#define PREP_XC 3125                  // 50000*64/4 float4s / 256
#define PREP_PE (PREP_XC + 1280)      // 1024*1280/4 / 256
#define PREP_PL (PREP_PE + 8)         // 16 coltiles * 2 kc * 64 lanes / 256
#define PREP_PR (PREP_PL + 8)
#define PREP_PP (PREP_PR + 160)       // 16 * 40 * 64 / 256

__device__ inline void pack_frag(const float* __restrict__ src, bf16* __restrict__ dst,
                                 int KC, int tid) {
  int lane = tid & 63;
  int chunk = tid >> 6;            // = c*KC + kc
  int c = chunk / KC, kc = chunk - c * KC;
  int kbase = kc * 32 + ((lane >> 4) * 8);
  int n = c * 16 + (lane & 15);
#pragma unroll
  for (int j = 0; j < 8; ++j)
    dst[(size_t)tid * 8 + j] = __float2bfloat16(src[(size_t)(kbase + j) * HID + n]);
}

__global__ __launch_bounds__(256) void k_prep(
    const float* __restrict__ x, const float* __restrict__ pe,
    const float* __restrict__ Wl, const float* __restrict__ Wr,
    const float* __restrict__ Wp,
    uint2* __restrict__ x2, uint2* __restrict__ pe2,
    bf16* __restrict__ Wl_pk, bf16* __restrict__ Wr_pk, bf16* __restrict__ Wp_pk) {
  int b = blockIdx.x;
  if (b < PREP_XC) {
    int tid = b * 256 + threadIdx.x;
    float4 v = ((const float4*)x)[tid];
    x2[tid] = make_uint2(bf16rne(v.x) | (bf16rne(v.y) << 16),
                         bf16rne(v.z) | (bf16rne(v.w) << 16));
  } else if (b < PREP_PE) {
    int tid = (b - PREP_XC) * 256 + threadIdx.x;
    float4 v = ((const float4*)pe)[tid];
    pe2[tid] = make_uint2(bf16rne(v.x) | (bf16rne(v.y) << 16),
                          bf16rne(v.z) | (bf16rne(v.w) << 16));
  } else if (b < PREP_PL) {
    pack_frag(Wl, Wl_pk, 2, (b - PREP_PE) * 256 + threadIdx.x);
  } else if (b < PREP_PR) {
    pack_frag(Wr, Wr_pk, 2, (b - PREP_PL) * 256 + threadIdx.x);
  } else {
    pack_frag(Wp, Wp_pk, 40, (b - PREP_PR) * 256 + threadIdx.x);
  }
}

// ---------------------------------------------------------------------------
// k_bucket: bin edges into NB coarse buckets (dst>>6), packed src|(dst&63)<<16
// (src < 65536 since N_NODES = 50000). Per-block LDS histogram + ONE global
// reservation atomic per (block,bucket) -> contiguous line-merged runs.
// ---------------------------------------------------------------------------
__global__ __launch_bounds__(256) void k_bucket(
    const int* __restrict__ ei, int* __restrict__ bcnt,
    unsigned* __restrict__ bped) {
  __shared__ int hist[NB];
  __shared__ int base[NB];
  const int t = threadIdx.x;
  const int e0 = blockIdx.x * EPB;
  for (int i = t; i < NB; i += 256) hist[i] = 0;
  __syncthreads();
  for (int i = t; i < EPB; i += 256) {
    int e = e0 + i;
    if (e < N_EDGES) atomicAdd(&hist[ei[N_EDGES + e] >> 6], 1);
  }
  __syncthreads();
  for (int i = t; i < NB; i += 256) {
    int c = hist[i];
    base[i] = (c > 0) ? atomicAdd(&bcnt[i], c) : 0;
    hist[i] = 0;  // reuse as local cursor
  }
  __syncthreads();
  for (int i = t; i < EPB; i += 256) {
    int e = e0 + i;
    if (e < N_EDGES) {
      int src = ei[e], dst = ei[N_EDGES + e];
      int bk = dst >> 6;
      int pos = base[bk] + atomicAdd(&hist[bk], 1);
      if (pos < BCAP)
        bped[(size_t)bk * BCAP + pos] = (unsigned)src | ((unsigned)(dst & 63) << 16);
    }
  }
}

// ---------------------------------------------------------------------------
// k_aggr2: one block per bucket. Counting-sort the bucket's <=2K edges by
// local node in LDS (cheap int LDS atomics), then REGISTER-accumulate the
// gather per node (round-4 k_gather structure: 16 lanes x uint2 features,
// 4 edge slots x 4-deep ILP = 16 loads in flight, shuffle slot-reduce).
// No float atomics anywhere.
// ---------------------------------------------------------------------------
__global__ __launch_bounds__(256) void k_aggr2(
    const uint2* __restrict__ x2, const unsigned* __restrict__ bped,
    const int* __restrict__ bcnt, uint2* __restrict__ a2) {
  __shared__ unsigned s_raw[BCAP];    // 8 KB
  __shared__ unsigned short s_e[BCAP];// 4 KB (src fits 16 bits)
  __shared__ int s_off[65];
  __shared__ int s_cur[64];
  const int t = threadIdx.x;
  const int b = blockIdx.x;
  const int nE = min(bcnt[b], BCAP);

  if (t < 64) s_cur[t] = 0;
  __syncthreads();
  // load + histogram by local node
  for (int i = t; i < nE; i += 256) {
    unsigned pk = bped[(size_t)b * BCAP + i];
    s_raw[i] = pk;
    atomicAdd(&s_cur[(pk >> 16) & 63], 1);
  }
  __syncthreads();
  // exclusive prefix over 64 counters (wave 0)
  if (t < 64) {
    int sc = s_cur[t];
#pragma unroll
    for (int off = 1; off < 64; off <<= 1) {
      int u = __shfl_up(sc, off);
      if (t >= off) sc += u;
    }
    s_off[t + 1] = sc;
    if (t == 0) s_off[0] = 0;
    s_cur[t] = 0;
  }
  __syncthreads();
  // scatter into node-sorted order
  for (int i = t; i < nE; i += 256) {
    unsigned pk = s_raw[i];
    int ld = (pk >> 16) & 63;
    int pos = s_off[ld] + atomicAdd(&s_cur[ld], 1);
    s_e[pos] = (unsigned short)(pk & 0xffffu);
  }
  __syncthreads();

  // per-node register gather: wave w handles nodes w, w+4, ...
  const int w = t >> 6, lane = t & 63;
  const int el = lane >> 4;      // edge slot (4 edges per step)
  const int fb = lane & 15;      // uint2 feature block
  for (int n = w; n < 64; n += 4) {
    const int beg = s_off[n], end = s_off[n + 1];
    float4 s0 = {0,0,0,0}, s1 = {0,0,0,0}, s2 = {0,0,0,0}, s3 = {0,0,0,0};
    int e = beg;
    for (; e + 16 <= end; e += 16) {
      int i0 = s_e[e + el],      i1 = s_e[e + 4 + el];
      int i2 = s_e[e + 8 + el],  i3 = s_e[e + 12 + el];
      uint2 v0 = x2[(size_t)i0 * 16 + fb];
      uint2 v1 = x2[(size_t)i1 * 16 + fb];
      uint2 v2 = x2[(size_t)i2 * 16 + fb];
      uint2 v3 = x2[(size_t)i3 * 16 + fb];
      acc_bf2(s0, v0); acc_bf2(s1, v1); acc_bf2(s2, v2); acc_bf2(s3, v3);
    }
    for (; e + 4 <= end; e += 4)
      acc_bf2(s0, x2[(size_t)s_e[e + el] * 16 + fb]);
    if (e + el < end)
      acc_bf2(s1, x2[(size_t)s_e[e + el] * 16 + fb]);
    float4 tt;
    tt.x = (s0.x + s1.x) + (s2.x + s3.x);
    tt.y = (s0.y + s1.y) + (s2.y + s3.y);
    tt.z = (s0.z + s1.z) + (s2.z + s3.z);
    tt.w = (s0.w + s1.w) + (s2.w + s3.w);
    tt.x += __shfl_xor(tt.x, 32); tt.x += __shfl_xor(tt.x, 16);
    tt.y += __shfl_xor(tt.y, 32); tt.y += __shfl_xor(tt.y, 16);
    tt.z += __shfl_xor(tt.z, 32); tt.z += __shfl_xor(tt.z, 16);
    tt.w += __shfl_xor(tt.w, 32); tt.w += __shfl_xor(tt.w, 16);
    const int node = b * 64 + n;
    if (el == 0 && node < N_NODES) {
      float inv = 1.0f / (float)max(end - beg, 1);
      uint2 o;
      o.x = bf16rne(tt.x * inv) | (bf16rne(tt.y * inv) << 16);
      o.y = bf16rne(tt.z * inv) | (bf16rne(tt.w * inv) << 16);
      a2[(size_t)node * 16 + fb] = o;
    }
  }
}

// ---------------------------------------------------------------------------
// k_mlp: pure MFMA GEMM [64 rows x 128] @ [128 x 256] + bias + relu ->
// drug (bf16). No LDS, no atomics, no divergent branches.
// ---------------------------------------------------------------------------
__global__ __launch_bounds__(256) void k_mlp(
    const bf16* __restrict__ aggrbf, const bf16* __restrict__ xbf,
    const bf16* __restrict__ Wl_pk, const bf16* __restrict__ Wr_pk,
    const float* __restrict__ bl, unsigned short* __restrict__ drug) {
  const int t = threadIdx.x, w = t >> 6, lane = t & 63;
  const int ml = lane & 15, q = lane >> 4;
  const int n0 = blockIdx.x * 64;

  f32x4 acc[4][4];
#pragma unroll
  for (int a = 0; a < 4; ++a)
#pragma unroll
    for (int c = 0; c < 4; ++c) acc[a][c] = (f32x4){0.f, 0.f, 0.f, 0.f};

#pragma unroll
  for (int mat = 0; mat < 2; ++mat) {
    const bf16* A = mat ? xbf : aggrbf;
    const bf16* B = mat ? Wr_pk : Wl_pk;
#pragma unroll
    for (int kc = 0; kc < 2; ++kc) {
      short8 af[4], bfr[4];
#pragma unroll
      for (int rt = 0; rt < 4; ++rt)
        af[rt] = *(const short8*)(A + (size_t)(n0 + rt * 16 + ml) * D_IN + kc * 32 + q * 8);
#pragma unroll
      for (int cl = 0; cl < 4; ++cl)
        bfr[cl] = *(const short8*)(B + ((size_t)((w * 4 + cl) * 2 + kc) * 64 + lane) * 8);
#pragma unroll
      for (int rt = 0; rt < 4; ++rt)
#pragma unroll
        for (int cl = 0; cl < 4; ++cl)
          acc[rt][cl] = __builtin_amdgcn_mfma_f32_16x16x32_bf16(af[rt], bfr[cl], acc[rt][cl], 0, 0, 0);
    }
  }

#pragma unroll
  for (int cl = 0; cl < 4; ++cl) {
    const int col = w * 64 + cl * 16 + ml;
    const float bias = bl[col];
#pragma unroll
    for (int rt = 0; rt < 4; ++rt) {
#pragma unroll
      for (int i = 0; i < 4; ++i) {
        const int row = n0 + rt * 16 + q * 4 + i;
        drug[(size_t)row * HID + col] =
            (unsigned short)bf16rne(fmaxf(acc[rt][cl][i] + bias, 0.f));
      }
    }
  }
}

// ---------------------------------------------------------------------------
// k_pool: one block per graph; binary search sorted batch for row range,
// column-sum drug rows (coalesced), write mean. Zero atomics.
// ---------------------------------------------------------------------------
__device__ inline int lb_dev(const int* __restrict__ a, int v) {
  int lo = 0, hi = N_NODES;
  while (lo < hi) { int m = (lo + hi) >> 1; if (a[m] < v) lo = m + 1; else hi = m; }
  return lo;
}

__global__ __launch_bounds__(256) void k_pool(
    const unsigned short* __restrict__ drug, const int* __restrict__ batch,
    float* __restrict__ pooled) {
  const int g = blockIdx.x, t = threadIdx.x;
  const int lo = lb_dev(batch, g);
  const int hi = lb_dev(batch, g + 1);
  float s0 = 0.f, s1 = 0.f, s2 = 0.f, s3 = 0.f;
  int r = lo;
  for (; r + 4 <= hi; r += 4) {
    s0 += __uint_as_float((unsigned)drug[(size_t)(r + 0) * HID + t] << 16);
    s1 += __uint_as_float((unsigned)drug[(size_t)(r + 1) * HID + t] << 16);
    s2 += __uint_as_float((unsigned)drug[(size_t)(r + 2) * HID + t] << 16);
    s3 += __uint_as_float((unsigned)drug[(size_t)(r + 3) * HID + t] << 16);
  }
  for (; r < hi; ++r)
    s0 += __uint_as_float((unsigned)drug[(size_t)r * HID + t] << 16);
  float inv = 1.0f / (float)max(hi - lo, 1);
  pooled[(size_t)g * HID + t] = ((s0 + s1) + (s2 + s3)) * inv;
}

// ---------------------------------------------------------------------------
// k_prot: pe[1024x1280] @ Wp[1280x256], K-split x4 -> prot4 partial slices.
// ---------------------------------------------------------------------------
__global__ __launch_bounds__(256) void k_prot(
    const bf16* __restrict__ pebf, const bf16* __restrict__ Wp_pk,
    float* __restrict__ prot4) {
  const int w = threadIdx.x >> 6, lane = threadIdx.x & 63;
  const int ml = lane & 15, q = lane >> 4;
  const int mt = blockIdx.x >> 2, ks = blockIdx.x & 3;
  const int g0 = mt * 16, kc0 = ks * 10;
  f32x4 acc[4];
#pragma unroll
  for (int c = 0; c < 4; ++c) acc[c] = (f32x4){0.f, 0.f, 0.f, 0.f};
  for (int kc = kc0; kc < kc0 + 10; ++kc) {
    short8 a = *(const short8*)(pebf + (size_t)(g0 + ml) * D_PROT + kc * 32 + q * 8);
#pragma unroll
    for (int cl = 0; cl < 4; ++cl) {
      short8 b = *(const short8*)(Wp_pk + ((size_t)((w * 4 + cl) * 40 + kc) * 64 + lane) * 8);
      acc[cl] = __builtin_amdgcn_mfma_f32_16x16x32_bf16(a, b, acc[cl], 0, 0, 0);
    }
  }
#pragma unroll
  for (int cl = 0; cl < 4; ++cl) {
    const int col = w * 64 + cl * 16 + ml;
#pragma unroll
    for (int i = 0; i < 4; ++i)
      prot4[((size_t)ks * N_GRAPHS + g0 + q * 4 + i) * HID + col] = acc[cl][i];
  }
}

// ---------------------------------------------------------------------------
// k_tail: combined = [pooled | sum(prot4)+bp]; inter = relu(@Wi+bi);
// out = inter@Wo + bo. Wave-shuffle head reduction.
// ---------------------------------------------------------------------------
__global__ __launch_bounds__(256) void k_tail(
    const float* __restrict__ pooled, const float* __restrict__ prot4,
    const float* __restrict__ bp,
    const float* __restrict__ Wi, const float* __restrict__ bi,
    const float* __restrict__ Wo, const float* __restrict__ bo,
    float* __restrict__ out) {
  __shared__ float sComb[GPB * 2 * HID];
  __shared__ float sRed[4 * GPB];
  const int t = threadIdx.x, w = t >> 6, lane = t & 63;
  const int g0 = blockIdx.x * GPB;

  for (int g = 0; g < GPB; ++g) {
    size_t idx = (size_t)(g0 + g) * HID + t;
    sComb[g * 2 * HID + t] = pooled[idx];
    float pr = prot4[idx] + prot4[(size_t)N_GRAPHS * HID + idx]
             + prot4[2 * (size_t)N_GRAPHS * HID + idx]
             + prot4[3 * (size_t)N_GRAPHS * HID + idx];
    sComb[g * 2 * HID + HID + t] = pr + bp[t];
  }
  __syncthreads();

  float acci[GPB];
  const float bit = bi[t];
#pragma unroll
  for (int g = 0; g < GPB; ++g) acci[g] = bit;
  for (int j = 0; j < 2 * HID; ++j) {
    float wv = Wi[j * HID + t];
#pragma unroll
    for (int g = 0; g < GPB; ++g) acci[g] = fmaf(sComb[g * 2 * HID + j], wv, acci[g]);
  }

  const float wo = Wo[t];
  float p[GPB];
#pragma unroll
  for (int g = 0; g < GPB; ++g) p[g] = fmaxf(acci[g], 0.f) * wo;
#pragma unroll
  for (int off = 32; off > 0; off >>= 1)
#pragma unroll
    for (int g = 0; g < GPB; ++g) p[g] += __shfl_down(p[g], off);
  if (lane == 0)
    for (int g = 0; g < GPB; ++g) sRed[w * GPB + g] = p[g];
  __syncthreads();
  if (t < GPB)
    out[g0 + t] = sRed[0 * GPB + t] + sRed[1 * GPB + t] + sRed[2 * GPB + t]
                + sRed[3 * GPB + t] + bo[0];
}

extern "C" void kernel_launch(void* const* d_in, const int* in_sizes, int n_in,
                              void* d_out, int out_size, void* d_ws, size_t ws_size,
                              hipStream_t stream) {
  const float* x     = (const float*)d_in[0];
  const float* pe    = (const float*)d_in[1];
  const float* Wl    = (const float*)d_in[2];
  const float* bl    = (const float*)d_in[3];
  const float* Wr    = (const float*)d_in[4];
  const float* Wp    = (const float*)d_in[5];
  const float* bp    = (const float*)d_in[6];
  const float* Wi    = (const float*)d_in[7];
  const float* bi    = (const float*)d_in[8];
  const float* Wo    = (const float*)d_in[9];
  const float* bo    = (const float*)d_in[10];
  const int*   ei    = (const int*)d_in[11];
  const int*   batch = (const int*)d_in[12];
  float* out = (float*)d_out;

  char* p = (char*)d_ws;
  auto alloc = [&](size_t bytes) {
    char* r = p;
    p += (bytes + 255) & ~(size_t)255;
    return r;
  };
  int*      bcnt  = (int*)alloc(NB * 4);
  size_t zbytes = (size_t)(p - (char*)d_ws);     // only bcnt needs zeroing
  unsigned* bped  = (unsigned*)alloc((size_t)NB * BCAP * 4);
  bf16*  xbf    = (bf16*)alloc((size_t)N_PAD * D_IN * 2);
  bf16*  aggrbf = (bf16*)alloc((size_t)N_PAD * D_IN * 2);
  bf16*  pebf   = (bf16*)alloc((size_t)N_GRAPHS * D_PROT * 2);
  bf16*  Wl_pk  = (bf16*)alloc((size_t)D_IN * HID * 2);
  bf16*  Wr_pk  = (bf16*)alloc((size_t)D_IN * HID * 2);
  bf16*  Wp_pk  = (bf16*)alloc((size_t)D_PROT * HID * 2);
  float* prot4  = (float*)alloc((size_t)4 * N_GRAPHS * HID * 4);
  unsigned short* drug = (unsigned short*)alloc((size_t)N_PAD * HID * 2);
  float* pooled = (float*)alloc((size_t)N_GRAPHS * HID * 4);

  hipMemsetAsync(d_ws, 0, zbytes, stream);

  k_prep<<<PREP_PP, 256, 0, stream>>>(x, pe, Wl, Wr, Wp,
                                      (uint2*)xbf, (uint2*)pebf,
                                      Wl_pk, Wr_pk, Wp_pk);
  k_bucket<<<NABLK, 256, 0, stream>>>(ei, bcnt, bped);
  k_aggr2<<<NB, 256, 0, stream>>>((const uint2*)xbf, bped, bcnt, (uint2*)aggrbf);
  k_prot<<<256, 256, 0, stream>>>(pebf, Wp_pk, prot4);
  k_mlp<<<N_PAD / 64, 256, 0, stream>>>(aggrbf, xbf, Wl_pk, Wr_pk, bl, drug);
  k_pool<<<N_GRAPHS, 256, 0, stream>>>(drug, batch, pooled);
  k_tail<<<N_GRAPHS / GPB, 256, 0, stream>>>(pooled, prot4, bp,
                                             Wi, bi, Wo, bo, out);
}

// Round 7
// 197.774 us; speedup vs baseline: 2.6445x; 1.0745x over previous
//
#include <hip/hip_runtime.h>
#include <hip/hip_bf16.h>

#define N_NODES 50000
#define N_EDGES 800000
#define N_GRAPHS 1024
#define D_IN 64
#define D_PROT 1280
#define HID 256
#define GPB 4
#define N_PAD 50048   // N_NODES padded to multiple of 64

// edge bucketing: 64 nodes per bucket
#define NB 782        // ceil(50048/64)
#define BCAP 2048     // capacity per bucket (mean 1023, max ~1200)
#define BEPB 4096     // edges per bucket-block
#define BBLK 196      // ceil(800000/4096)

typedef __attribute__((ext_vector_type(8))) short short8;
typedef __attribute__((ext_vector_type(4))) float f32x4;
typedef __hip_bfloat16 bf16;

// round-to-nearest-even f32 -> bf16 bits (finite inputs only)
__device__ inline unsigned bf16rne(float f) {
  unsigned u = __float_as_uint(f);
  return (u + 0x7fffu + ((u >> 16) & 1u)) >> 16;
}
// accumulate 4 bf16 packed in uint2 into float4
__device__ inline void acc_bf2(float4& a, uint2 v) {
  a.x += __uint_as_float(v.x << 16);
  a.y += __uint_as_float(v.x & 0xffff0000u);
  a.z += __uint_as_float(v.y << 16);
  a.w += __uint_as_float(v.y & 0xffff0000u);
}

// ---------------------------------------------------------------------------
// K1 "front": blockIdx [0,BBLK) = edge bucketing (4-deep unrolled, latency-
// bound) ∪ [BBLK, BBLK+PREP_PP) = conversions + weight packing (BW-bound).
// Independent work; fusion lets the scheduler overlap the two regimes.
// ---------------------------------------------------------------------------
#define PREP_XC 3125                  // 50000*64/4 float4s / 256
#define PREP_PE (PREP_XC + 1280)      // 1024*1280/4 / 256
#define PREP_PL (PREP_PE + 8)         // 16 coltiles * 2 kc * 64 lanes / 256
#define PREP_PR (PREP_PL + 8)
#define PREP_PP (PREP_PR + 160)       // 16 * 40 * 64 / 256

__device__ inline void pack_frag(const float* __restrict__ src, bf16* __restrict__ dst,
                                 int KC, int tid) {
  int lane = tid & 63;
  int chunk = tid >> 6;            // = c*KC + kc
  int c = chunk / KC, kc = chunk - c * KC;
  int kbase = kc * 32 + ((lane >> 4) * 8);
  int n = c * 16 + (lane & 15);
#pragma unroll
  for (int j = 0; j < 8; ++j)
    dst[(size_t)tid * 8 + j] = __float2bfloat16(src[(size_t)(kbase + j) * HID + n]);
}

__global__ __launch_bounds__(256) void k_front(
    const float* __restrict__ x, const float* __restrict__ pe,
    const float* __restrict__ Wl, const float* __restrict__ Wr,
    const float* __restrict__ Wp, const int* __restrict__ ei,
    uint2* __restrict__ x2, uint2* __restrict__ pe2,
    bf16* __restrict__ Wl_pk, bf16* __restrict__ Wr_pk, bf16* __restrict__ Wp_pk,
    int* __restrict__ bcnt, unsigned* __restrict__ bped) {
  __shared__ int hist[NB];
  __shared__ int base[NB];
  const int b = blockIdx.x;
  const int t = threadIdx.x;
  if (b < BBLK) {
    const int e0 = b * BEPB;
    for (int i = t; i < NB; i += 256) hist[i] = 0;
    __syncthreads();
    // pass A: histogram by coarse bucket, 4 independent loads per step
    for (int i = t; i < BEPB; i += 1024) {
      int d[4]; bool v[4];
#pragma unroll
      for (int u = 0; u < 4; ++u) {
        int idx = i + u * 256;
        v[u] = (e0 + idx < N_EDGES);
        d[u] = v[u] ? ei[N_EDGES + e0 + idx] : 0;
      }
#pragma unroll
      for (int u = 0; u < 4; ++u)
        if (v[u]) atomicAdd(&hist[d[u] >> 6], 1);
    }
    __syncthreads();
    // reservation: ONE global atomic per (block,bucket)
    for (int i = t; i < NB; i += 256) {
      int c = hist[i];
      base[i] = (c > 0) ? atomicAdd(&bcnt[i], c) : 0;
      hist[i] = 0;  // reuse as local cursor
    }
    __syncthreads();
    // pass B: scatter packed src|(local)<<16 into contiguous runs
    for (int i = t; i < BEPB; i += 1024) {
      int s[4], d[4]; bool v[4];
#pragma unroll
      for (int u = 0; u < 4; ++u) {
        int idx = i + u * 256;
        v[u] = (e0 + idx < N_EDGES);
        s[u] = v[u] ? ei[e0 + idx] : 0;
        d[u] = v[u] ? ei[N_EDGES + e0 + idx] : 0;
      }
#pragma unroll
      for (int u = 0; u < 4; ++u) {
        if (v[u]) {
          int bk = d[u] >> 6;
          int pos = base[bk] + atomicAdd(&hist[bk], 1);
          if (pos < BCAP)
            bped[(size_t)bk * BCAP + pos] =
                (unsigned)s[u] | ((unsigned)(d[u] & 63) << 16);
        }
      }
    }
    return;
  }
  const int pb = b - BBLK;
  if (pb < PREP_XC) {
    int tid = pb * 256 + t;
    float4 v = ((const float4*)x)[tid];
    x2[tid] = make_uint2(bf16rne(v.x) | (bf16rne(v.y) << 16),
                         bf16rne(v.z) | (bf16rne(v.w) << 16));
  } else if (pb < PREP_PE) {
    int tid = (pb - PREP_XC) * 256 + t;
    float4 v = ((const float4*)pe)[tid];
    pe2[tid] = make_uint2(bf16rne(v.x) | (bf16rne(v.y) << 16),
                          bf16rne(v.z) | (bf16rne(v.w) << 16));
  } else if (pb < PREP_PL) {
    pack_frag(Wl, Wl_pk, 2, (pb - PREP_PE) * 256 + t);
  } else if (pb < PREP_PR) {
    pack_frag(Wr, Wr_pk, 2, (pb - PREP_PL) * 256 + t);
  } else {
    pack_frag(Wp, Wp_pk, 40, (pb - PREP_PR) * 256 + t);
  }
}

// ---------------------------------------------------------------------------
// K2 "mid": blockIdx [0,NB) = neighbor aggregation (counting-sort in LDS +
// register gather, memory-bound) ∪ [NB,NB+256) = protein GEMM K-split
// (MFMA-bound). Both depend only on K1 outputs; fusion overlaps the pipes.
// ---------------------------------------------------------------------------
__global__ __launch_bounds__(256) void k_mid(
    const uint2* __restrict__ x2, const unsigned* __restrict__ bped,
    const int* __restrict__ bcnt, uint2* __restrict__ a2,
    const bf16* __restrict__ pebf, const bf16* __restrict__ Wp_pk,
    float* __restrict__ prot4) {
  __shared__ unsigned s_raw[BCAP];     // 8 KB
  __shared__ unsigned short s_e[BCAP]; // 4 KB
  __shared__ int s_off[65];
  __shared__ int s_cur[64];
  const int t = threadIdx.x;
  if (blockIdx.x < NB) {
    const int b = blockIdx.x;
    const int nE = min(bcnt[b], BCAP);
    if (t < 64) s_cur[t] = 0;
    __syncthreads();
    for (int i = t; i < nE; i += 256) {
      unsigned pk = bped[(size_t)b * BCAP + i];
      s_raw[i] = pk;
      atomicAdd(&s_cur[(pk >> 16) & 63], 1);
    }
    __syncthreads();
    if (t < 64) {
      int sc = s_cur[t];
#pragma unroll
      for (int off = 1; off < 64; off <<= 1) {
        int u = __shfl_up(sc, off);
        if (t >= off) sc += u;
      }
      s_off[t + 1] = sc;
      if (t == 0) s_off[0] = 0;
      s_cur[t] = 0;
    }
    __syncthreads();
    for (int i = t; i < nE; i += 256) {
      unsigned pk = s_raw[i];
      int ld = (pk >> 16) & 63;
      int pos = s_off[ld] + atomicAdd(&s_cur[ld], 1);
      s_e[pos] = (unsigned short)(pk & 0xffffu);
    }
    __syncthreads();

    // per-node register gather: wave w handles nodes w, w+4, ...
    const int w = t >> 6, lane = t & 63;
    const int el = lane >> 4;      // edge slot (4 edges per step)
    const int fb = lane & 15;      // uint2 feature block
    for (int n = w; n < 64; n += 4) {
      const int beg = s_off[n], end = s_off[n + 1];
      float4 s0 = {0,0,0,0}, s1 = {0,0,0,0}, s2 = {0,0,0,0}, s3 = {0,0,0,0};
      int e = beg;
      for (; e + 16 <= end; e += 16) {
        int i0 = s_e[e + el],     i1 = s_e[e + 4 + el];
        int i2 = s_e[e + 8 + el], i3 = s_e[e + 12 + el];
        uint2 v0 = x2[(size_t)i0 * 16 + fb];
        uint2 v1 = x2[(size_t)i1 * 16 + fb];
        uint2 v2 = x2[(size_t)i2 * 16 + fb];
        uint2 v3 = x2[(size_t)i3 * 16 + fb];
        acc_bf2(s0, v0); acc_bf2(s1, v1); acc_bf2(s2, v2); acc_bf2(s3, v3);
      }
      for (; e + 4 <= end; e += 4)
        acc_bf2(s0, x2[(size_t)s_e[e + el] * 16 + fb]);
      if (e + el < end)
        acc_bf2(s1, x2[(size_t)s_e[e + el] * 16 + fb]);
      float4 tt;
      tt.x = (s0.x + s1.x) + (s2.x + s3.x);
      tt.y = (s0.y + s1.y) + (s2.y + s3.y);
      tt.z = (s0.z + s1.z) + (s2.z + s3.z);
      tt.w = (s0.w + s1.w) + (s2.w + s3.w);
      tt.x += __shfl_xor(tt.x, 32); tt.x += __shfl_xor(tt.x, 16);
      tt.y += __shfl_xor(tt.y, 32); tt.y += __shfl_xor(tt.y, 16);
      tt.z += __shfl_xor(tt.z, 32); tt.z += __shfl_xor(tt.z, 16);
      tt.w += __shfl_xor(tt.w, 32); tt.w += __shfl_xor(tt.w, 16);
      const int node = b * 64 + n;
      if (el == 0 && node < N_NODES) {
        float inv = 1.0f / (float)max(end - beg, 1);
        uint2 o;
        o.x = bf16rne(tt.x * inv) | (bf16rne(tt.y * inv) << 16);
        o.y = bf16rne(tt.z * inv) | (bf16rne(tt.w * inv) << 16);
        a2[(size_t)node * 16 + fb] = o;
      }
    }
    return;
  }
  // protein GEMM: pe[1024x1280] @ Wp[1280x256], K-split x4 partials
  const int kb = blockIdx.x - NB;
  const int w = t >> 6, lane = t & 63;
  const int ml = lane & 15, q = lane >> 4;
  const int mt = kb >> 2, ks = kb & 3;
  const int g0 = mt * 16, kc0 = ks * 10;
  f32x4 acc[4];
#pragma unroll
  for (int c = 0; c < 4; ++c) acc[c] = (f32x4){0.f, 0.f, 0.f, 0.f};
  for (int kc = kc0; kc < kc0 + 10; ++kc) {
    short8 a = *(const short8*)(pebf + (size_t)(g0 + ml) * D_PROT + kc * 32 + q * 8);
#pragma unroll
    for (int cl = 0; cl < 4; ++cl) {
      short8 bb = *(const short8*)(Wp_pk + ((size_t)((w * 4 + cl) * 40 + kc) * 64 + lane) * 8);
      acc[cl] = __builtin_amdgcn_mfma_f32_16x16x32_bf16(a, bb, acc[cl], 0, 0, 0);
    }
  }
#pragma unroll
  for (int cl = 0; cl < 4; ++cl) {
    const int col = w * 64 + cl * 16 + ml;
#pragma unroll
    for (int i = 0; i < 4; ++i)
      prot4[((size_t)ks * N_GRAPHS + g0 + q * 4 + i) * HID + col] = acc[cl][i];
  }
}

// ---------------------------------------------------------------------------
// k_mlp: pure MFMA GEMM [64 rows x 128] @ [128 x 256] + bias + relu ->
// drug (bf16). No LDS, no atomics, no divergent branches.
// ---------------------------------------------------------------------------
__global__ __launch_bounds__(256) void k_mlp(
    const bf16* __restrict__ aggrbf, const bf16* __restrict__ xbf,
    const bf16* __restrict__ Wl_pk, const bf16* __restrict__ Wr_pk,
    const float* __restrict__ bl, unsigned short* __restrict__ drug) {
  const int t = threadIdx.x, w = t >> 6, lane = t & 63;
  const int ml = lane & 15, q = lane >> 4;
  const int n0 = blockIdx.x * 64;

  f32x4 acc[4][4];
#pragma unroll
  for (int a = 0; a < 4; ++a)
#pragma unroll
    for (int c = 0; c < 4; ++c) acc[a][c] = (f32x4){0.f, 0.f, 0.f, 0.f};

#pragma unroll
  for (int mat = 0; mat < 2; ++mat) {
    const bf16* A = mat ? xbf : aggrbf;
    const bf16* B = mat ? Wr_pk : Wl_pk;
#pragma unroll
    for (int kc = 0; kc < 2; ++kc) {
      short8 af[4], bfr[4];
#pragma unroll
      for (int rt = 0; rt < 4; ++rt)
        af[rt] = *(const short8*)(A + (size_t)(n0 + rt * 16 + ml) * D_IN + kc * 32 + q * 8);
#pragma unroll
      for (int cl = 0; cl < 4; ++cl)
        bfr[cl] = *(const short8*)(B + ((size_t)((w * 4 + cl) * 2 + kc) * 64 + lane) * 8);
#pragma unroll
      for (int rt = 0; rt < 4; ++rt)
#pragma unroll
        for (int cl = 0; cl < 4; ++cl)
          acc[rt][cl] = __builtin_amdgcn_mfma_f32_16x16x32_bf16(af[rt], bfr[cl], acc[rt][cl], 0, 0, 0);
    }
  }

#pragma unroll
  for (int cl = 0; cl < 4; ++cl) {
    const int col = w * 64 + cl * 16 + ml;
    const float bias = bl[col];
#pragma unroll
    for (int rt = 0; rt < 4; ++rt) {
#pragma unroll
      for (int i = 0; i < 4; ++i) {
        const int row = n0 + rt * 16 + q * 4 + i;
        drug[(size_t)row * HID + col] =
            (unsigned short)bf16rne(fmaxf(acc[rt][cl][i] + bias, 0.f));
      }
    }
  }
}

// ---------------------------------------------------------------------------
// K4 "back": pool + tail fused, one block per GPB graphs. Binary-search the
// sorted batch, column-sum drug rows straight into sComb (no pooled buffer),
// add protein partials, then interaction + head.
// ---------------------------------------------------------------------------
__device__ inline int lb_dev(const int* __restrict__ a, int v) {
  int lo = 0, hi = N_NODES;
  while (lo < hi) { int m = (lo + hi) >> 1; if (a[m] < v) lo = m + 1; else hi = m; }
  return lo;
}

__global__ __launch_bounds__(256) void k_back(
    const unsigned short* __restrict__ drug, const int* __restrict__ batch,
    const float* __restrict__ prot4, const float* __restrict__ bp,
    const float* __restrict__ Wi, const float* __restrict__ bi,
    const float* __restrict__ Wo, const float* __restrict__ bo,
    float* __restrict__ out) {
  __shared__ float sComb[GPB * 2 * HID];
  __shared__ float sRed[4 * GPB];
  const int t = threadIdx.x, w = t >> 6, lane = t & 63;
  const int g0 = blockIdx.x * GPB;

  for (int g = 0; g < GPB; ++g) {
    const int gg = g0 + g;
    const int lo = lb_dev(batch, gg);
    const int hi = lb_dev(batch, gg + 1);
    float s0 = 0.f, s1 = 0.f, s2 = 0.f, s3 = 0.f;
    int r = lo;
    for (; r + 4 <= hi; r += 4) {
      s0 += __uint_as_float((unsigned)drug[(size_t)(r + 0) * HID + t] << 16);
      s1 += __uint_as_float((unsigned)drug[(size_t)(r + 1) * HID + t] << 16);
      s2 += __uint_as_float((unsigned)drug[(size_t)(r + 2) * HID + t] << 16);
      s3 += __uint_as_float((unsigned)drug[(size_t)(r + 3) * HID + t] << 16);
    }
    for (; r < hi; ++r)
      s0 += __uint_as_float((unsigned)drug[(size_t)r * HID + t] << 16);
    float inv = 1.0f / (float)max(hi - lo, 1);
    sComb[g * 2 * HID + t] = ((s0 + s1) + (s2 + s3)) * inv;
    size_t idx = (size_t)gg * HID + t;
    float pr = prot4[idx] + prot4[(size_t)N_GRAPHS * HID + idx]
             + prot4[2 * (size_t)N_GRAPHS * HID + idx]
             + prot4[3 * (size_t)N_GRAPHS * HID + idx];
    sComb[g * 2 * HID + HID + t] = pr + bp[t];
  }
  __syncthreads();

  float acci[GPB];
  const float bit = bi[t];
#pragma unroll
  for (int g = 0; g < GPB; ++g) acci[g] = bit;
  for (int j = 0; j < 2 * HID; ++j) {
    float wv = Wi[j * HID + t];
#pragma unroll
    for (int g = 0; g < GPB; ++g) acci[g] = fmaf(sComb[g * 2 * HID + j], wv, acci[g]);
  }

  const float wo = Wo[t];
  float p[GPB];
#pragma unroll
  for (int g = 0; g < GPB; ++g) p[g] = fmaxf(acci[g], 0.f) * wo;
#pragma unroll
  for (int off = 32; off > 0; off >>= 1)
#pragma unroll
    for (int g = 0; g < GPB; ++g) p[g] += __shfl_down(p[g], off);
  if (lane == 0)
    for (int g = 0; g < GPB; ++g) sRed[w * GPB + g] = p[g];
  __syncthreads();
  if (t < GPB)
    out[g0 + t] = sRed[0 * GPB + t] + sRed[1 * GPB + t] + sRed[2 * GPB + t]
                + sRed[3 * GPB + t] + bo[0];
}

extern "C" void kernel_launch(void* const* d_in, const int* in_sizes, int n_in,
                              void* d_out, int out_size, void* d_ws, size_t ws_size,
                              hipStream_t stream) {
  const float* x     = (const float*)d_in[0];
  const float* pe    = (const float*)d_in[1];
  const float* Wl    = (const float*)d_in[2];
  const float* bl    = (const float*)d_in[3];
  const float* Wr    = (const float*)d_in[4];
  const float* Wp    = (const float*)d_in[5];
  const float* bp    = (const float*)d_in[6];
  const float* Wi    = (const float*)d_in[7];
  const float* bi    = (const float*)d_in[8];
  const float* Wo    = (const float*)d_in[9];
  const float* bo    = (const float*)d_in[10];
  const int*   ei    = (const int*)d_in[11];
  const int*   batch = (const int*)d_in[12];
  float* out = (float*)d_out;

  char* p = (char*)d_ws;
  auto alloc = [&](size_t bytes) {
    char* r = p;
    p += (bytes + 255) & ~(size_t)255;
    return r;
  };
  int*      bcnt  = (int*)alloc(NB * 4);
  size_t zbytes = (size_t)(p - (char*)d_ws);     // only bcnt needs zeroing
  unsigned* bped  = (unsigned*)alloc((size_t)NB * BCAP * 4);
  bf16*  xbf    = (bf16*)alloc((size_t)N_PAD * D_IN * 2);
  bf16*  aggrbf = (bf16*)alloc((size_t)N_PAD * D_IN * 2);
  bf16*  pebf   = (bf16*)alloc((size_t)N_GRAPHS * D_PROT * 2);
  bf16*  Wl_pk  = (bf16*)alloc((size_t)D_IN * HID * 2);
  bf16*  Wr_pk  = (bf16*)alloc((size_t)D_IN * HID * 2);
  bf16*  Wp_pk  = (bf16*)alloc((size_t)D_PROT * HID * 2);
  float* prot4  = (float*)alloc((size_t)4 * N_GRAPHS * HID * 4);
  unsigned short* drug = (unsigned short*)alloc((size_t)N_PAD * HID * 2);

  hipMemsetAsync(d_ws, 0, zbytes, stream);

  k_front<<<BBLK + PREP_PP, 256, 0, stream>>>(
      x, pe, Wl, Wr, Wp, ei,
      (uint2*)xbf, (uint2*)pebf, Wl_pk, Wr_pk, Wp_pk, bcnt, bped);
  k_mid<<<NB + 256, 256, 0, stream>>>(
      (const uint2*)xbf, bped, bcnt, (uint2*)aggrbf, pebf, Wp_pk, prot4);
  k_mlp<<<N_PAD / 64, 256, 0, stream>>>(aggrbf, xbf, Wl_pk, Wr_pk, bl, drug);
  k_back<<<N_GRAPHS / GPB, 256, 0, stream>>>(
      drug, batch, prot4, bp, Wi, bi, Wo, bo, out);
}

// Round 9
// 171.119 us; speedup vs baseline: 3.0564x; 1.1558x over previous
//
#include <hip/hip_runtime.h>
#include <hip/hip_bf16.h>

#define N_NODES 50000
#define N_EDGES 800000
#define N_GRAPHS 1024
#define D_IN 64
#define D_PROT 1280
#define HID 256
#define N_PAD 50048   // N_NODES padded to multiple of 64

// edge bucketing: 64 nodes per bucket
#define NB 782        // ceil(50048/64)
#define BCAP 2048     // capacity per bucket (mean 1023, max ~1200)
#define BEPB 4096     // edges per bucket-block
#define BBLK 196      // ceil(800000/4096)

typedef __attribute__((ext_vector_type(8))) short short8;
typedef __attribute__((ext_vector_type(4))) float f32x4;
typedef __hip_bfloat16 bf16;

// round-to-nearest-even f32 -> bf16 bits (finite inputs only)
__device__ inline unsigned bf16rne(float f) {
  unsigned u = __float_as_uint(f);
  return (u + 0x7fffu + ((u >> 16) & 1u)) >> 16;
}
// accumulate 4 bf16 packed in uint2 into float4
__device__ inline void acc_bf2(float4& a, uint2 v) {
  a.x += __uint_as_float(v.x << 16);
  a.y += __uint_as_float(v.x & 0xffff0000u);
  a.z += __uint_as_float(v.y << 16);
  a.w += __uint_as_float(v.y & 0xffff0000u);
}

// ---------------------------------------------------------------------------
// K1 "front": blockIdx [0,BBLK) = edge bucketing (4-deep unrolled, latency-
// bound) ∪ rest = conversions + weight packing (BW-bound). Wi packed too.
// ---------------------------------------------------------------------------
#define PREP_XC 3125                  // 50000*64/4 float4s / 256
#define PREP_PE (PREP_XC + 1280)      // 1024*1280/4 / 256
#define PREP_PL (PREP_PE + 8)         // Wl: 16 coltiles * 2 kc * 64 / 256
#define PREP_PR (PREP_PL + 8)         // Wr
#define PREP_WP (PREP_PR + 160)       // Wp: 16 * 40 * 64 / 256
#define PREP_WI (PREP_WP + 64)        // Wi: 16 * 16 * 64 / 256

__device__ inline void pack_frag(const float* __restrict__ src, bf16* __restrict__ dst,
                                 int KC, int tid) {
  int lane = tid & 63;
  int chunk = tid >> 6;            // = c*KC + kc
  int c = chunk / KC, kc = chunk - c * KC;
  int kbase = kc * 32 + ((lane >> 4) * 8);
  int n = c * 16 + (lane & 15);
#pragma unroll
  for (int j = 0; j < 8; ++j)
    dst[(size_t)tid * 8 + j] = __float2bfloat16(src[(size_t)(kbase + j) * HID + n]);
}

__global__ __launch_bounds__(256) void k_front(
    const float* __restrict__ x, const float* __restrict__ pe,
    const float* __restrict__ Wl, const float* __restrict__ Wr,
    const float* __restrict__ Wp, const float* __restrict__ Wi,
    const int* __restrict__ ei,
    uint2* __restrict__ x2, uint2* __restrict__ pe2,
    bf16* __restrict__ Wl_pk, bf16* __restrict__ Wr_pk,
    bf16* __restrict__ Wp_pk, bf16* __restrict__ Wi_pk,
    int* __restrict__ bcnt, unsigned* __restrict__ bped) {
  __shared__ int hist[NB];
  __shared__ int base[NB];
  const int b = blockIdx.x;
  const int t = threadIdx.x;
  if (b < BBLK) {
    const int e0 = b * BEPB;
    for (int i = t; i < NB; i += 256) hist[i] = 0;
    __syncthreads();
    // pass A: histogram by coarse bucket, 4 independent loads per step
    for (int i = t; i < BEPB; i += 1024) {
      int d[4]; bool v[4];
#pragma unroll
      for (int u = 0; u < 4; ++u) {
        int idx = i + u * 256;
        v[u] = (e0 + idx < N_EDGES);
        d[u] = v[u] ? ei[N_EDGES + e0 + idx] : 0;
      }
#pragma unroll
      for (int u = 0; u < 4; ++u)
        if (v[u]) atomicAdd(&hist[d[u] >> 6], 1);
    }
    __syncthreads();
    // reservation: ONE global atomic per (block,bucket)
    for (int i = t; i < NB; i += 256) {
      int c = hist[i];
      base[i] = (c > 0) ? atomicAdd(&bcnt[i], c) : 0;
      hist[i] = 0;  // reuse as local cursor
    }
    __syncthreads();
    // pass B: scatter packed src|(local)<<16 into contiguous runs
    for (int i = t; i < BEPB; i += 1024) {
      int s[4], d[4]; bool v[4];
#pragma unroll
      for (int u = 0; u < 4; ++u) {
        int idx = i + u * 256;
        v[u] = (e0 + idx < N_EDGES);
        s[u] = v[u] ? ei[e0 + idx] : 0;
        d[u] = v[u] ? ei[N_EDGES + e0 + idx] : 0;
      }
#pragma unroll
      for (int u = 0; u < 4; ++u) {
        if (v[u]) {
          int bk = d[u] >> 6;
          int pos = base[bk] + atomicAdd(&hist[bk], 1);
          if (pos < BCAP)
            bped[(size_t)bk * BCAP + pos] =
                (unsigned)s[u] | ((unsigned)(d[u] & 63) << 16);
        }
      }
    }
    return;
  }
  const int pb = b - BBLK;
  if (pb < PREP_XC) {
    int tid = pb * 256 + t;
    float4 v = ((const float4*)x)[tid];
    x2[tid] = make_uint2(bf16rne(v.x) | (bf16rne(v.y) << 16),
                         bf16rne(v.z) | (bf16rne(v.w) << 16));
  } else if (pb < PREP_PE) {
    int tid = (pb - PREP_XC) * 256 + t;
    float4 v = ((const float4*)pe)[tid];
    pe2[tid] = make_uint2(bf16rne(v.x) | (bf16rne(v.y) << 16),
                          bf16rne(v.z) | (bf16rne(v.w) << 16));
  } else if (pb < PREP_PL) {
    pack_frag(Wl, Wl_pk, 2, (pb - PREP_PE) * 256 + t);
  } else if (pb < PREP_PR) {
    pack_frag(Wr, Wr_pk, 2, (pb - PREP_PL) * 256 + t);
  } else if (pb < PREP_WP) {
    pack_frag(Wp, Wp_pk, 40, (pb - PREP_PR) * 256 + t);
  } else {
    pack_frag(Wi, Wi_pk, 16, (pb - PREP_WP) * 256 + t);
  }
}

// ---------------------------------------------------------------------------
// K2 "mid": blockIdx [0,NB) = neighbor aggregation (counting-sort in LDS +
// register gather) ∪ [NB,NB+256) = protein GEMM K-split x4 (MFMA).
// ---------------------------------------------------------------------------
__global__ __launch_bounds__(256) void k_mid(
    const uint2* __restrict__ x2, const unsigned* __restrict__ bped,
    const int* __restrict__ bcnt, uint2* __restrict__ a2,
    const bf16* __restrict__ pebf, const bf16* __restrict__ Wp_pk,
    float* __restrict__ prot4) {
  __shared__ unsigned s_raw[BCAP];     // 8 KB
  __shared__ unsigned short s_e[BCAP]; // 4 KB
  __shared__ int s_off[65];
  __shared__ int s_cur[64];
  const int t = threadIdx.x;
  if (blockIdx.x < NB) {
    const int b = blockIdx.x;
    const int nE = min(bcnt[b], BCAP);
    if (t < 64) s_cur[t] = 0;
    __syncthreads();
    for (int i = t; i < nE; i += 256) {
      unsigned pk = bped[(size_t)b * BCAP + i];
      s_raw[i] = pk;
      atomicAdd(&s_cur[(pk >> 16) & 63], 1);
    }
    __syncthreads();
    if (t < 64) {
      int sc = s_cur[t];
#pragma unroll
      for (int off = 1; off < 64; off <<= 1) {
        int u = __shfl_up(sc, off);
        if (t >= off) sc += u;
      }
      s_off[t + 1] = sc;
      if (t == 0) s_off[0] = 0;
      s_cur[t] = 0;
    }
    __syncthreads();
    for (int i = t; i < nE; i += 256) {
      unsigned pk = s_raw[i];
      int ld = (pk >> 16) & 63;
      int pos = s_off[ld] + atomicAdd(&s_cur[ld], 1);
      s_e[pos] = (unsigned short)(pk & 0xffffu);
    }
    __syncthreads();

    // per-node register gather: wave w handles nodes w, w+4, ...
    const int w = t >> 6, lane = t & 63;
    const int el = lane >> 4;      // edge slot (4 edges per step)
    const int fb = lane & 15;      // uint2 feature block
    for (int n = w; n < 64; n += 4) {
      const int beg = s_off[n], end = s_off[n + 1];
      float4 s0 = {0,0,0,0}, s1 = {0,0,0,0}, s2 = {0,0,0,0}, s3 = {0,0,0,0};
      int e = beg;
      for (; e + 16 <= end; e += 16) {
        int i0 = s_e[e + el],     i1 = s_e[e + 4 + el];
        int i2 = s_e[e + 8 + el], i3 = s_e[e + 12 + el];
        uint2 v0 = x2[(size_t)i0 * 16 + fb];
        uint2 v1 = x2[(size_t)i1 * 16 + fb];
        uint2 v2 = x2[(size_t)i2 * 16 + fb];
        uint2 v3 = x2[(size_t)i3 * 16 + fb];
        acc_bf2(s0, v0); acc_bf2(s1, v1); acc_bf2(s2, v2); acc_bf2(s3, v3);
      }
      for (; e + 4 <= end; e += 4)
        acc_bf2(s0, x2[(size_t)s_e[e + el] * 16 + fb]);
      if (e + el < end)
        acc_bf2(s1, x2[(size_t)s_e[e + el] * 16 + fb]);
      float4 tt;
      tt.x = (s0.x + s1.x) + (s2.x + s3.x);
      tt.y = (s0.y + s1.y) + (s2.y + s3.y);
      tt.z = (s0.z + s1.z) + (s2.z + s3.z);
      tt.w = (s0.w + s1.w) + (s2.w + s3.w);
      tt.x += __shfl_xor(tt.x, 32); tt.x += __shfl_xor(tt.x, 16);
      tt.y += __shfl_xor(tt.y, 32); tt.y += __shfl_xor(tt.y, 16);
      tt.z += __shfl_xor(tt.z, 32); tt.z += __shfl_xor(tt.z, 16);
      tt.w += __shfl_xor(tt.w, 32); tt.w += __shfl_xor(tt.w, 16);
      const int node = b * 64 + n;
      if (el == 0 && node < N_NODES) {
        float inv = 1.0f / (float)max(end - beg, 1);
        uint2 o;
        o.x = bf16rne(tt.x * inv) | (bf16rne(tt.y * inv) << 16);
        o.y = bf16rne(tt.z * inv) | (bf16rne(tt.w * inv) << 16);
        a2[(size_t)node * 16 + fb] = o;
      }
    }
    return;
  }
  // protein GEMM: pe[1024x1280] @ Wp[1280x256], K-split x4 partials
  const int kb = blockIdx.x - NB;
  const int w = t >> 6, lane = t & 63;
  const int ml = lane & 15, q = lane >> 4;
  const int mt = kb >> 2, ks = kb & 3;
  const int g0 = mt * 16, kc0 = ks * 10;
  f32x4 acc[4];
#pragma unroll
  for (int c = 0; c < 4; ++c) acc[c] = (f32x4){0.f, 0.f, 0.f, 0.f};
  for (int kc = kc0; kc < kc0 + 10; ++kc) {
    short8 a = *(const short8*)(pebf + (size_t)(g0 + ml) * D_PROT + kc * 32 + q * 8);
#pragma unroll
    for (int cl = 0; cl < 4; ++cl) {
      short8 bb = *(const short8*)(Wp_pk + ((size_t)((w * 4 + cl) * 40 + kc) * 64 + lane) * 8);
      acc[cl] = __builtin_amdgcn_mfma_f32_16x16x32_bf16(a, bb, acc[cl], 0, 0, 0);
    }
  }
#pragma unroll
  for (int cl = 0; cl < 4; ++cl) {
    const int col = w * 64 + cl * 16 + ml;
#pragma unroll
    for (int i = 0; i < 4; ++i)
      prot4[((size_t)ks * N_GRAPHS + g0 + q * 4 + i) * HID + col] = acc[cl][i];
  }
}

// ---------------------------------------------------------------------------
// k_mlp: pure MFMA GEMM [64 rows x 128] @ [128 x 256] + bias + relu ->
// drug (bf16). No LDS, no atomics, no divergent branches.
// ---------------------------------------------------------------------------
__global__ __launch_bounds__(256) void k_mlp(
    const bf16* __restrict__ aggrbf, const bf16* __restrict__ xbf,
    const bf16* __restrict__ Wl_pk, const bf16* __restrict__ Wr_pk,
    const float* __restrict__ bl, unsigned short* __restrict__ drug) {
  const int t = threadIdx.x, w = t >> 6, lane = t & 63;
  const int ml = lane & 15, q = lane >> 4;
  const int n0 = blockIdx.x * 64;

  f32x4 acc[4][4];
#pragma unroll
  for (int a = 0; a < 4; ++a)
#pragma unroll
    for (int c = 0; c < 4; ++c) acc[a][c] = (f32x4){0.f, 0.f, 0.f, 0.f};

#pragma unroll
  for (int mat = 0; mat < 2; ++mat) {
    const bf16* A = mat ? xbf : aggrbf;
    const bf16* B = mat ? Wr_pk : Wl_pk;
#pragma unroll
    for (int kc = 0; kc < 2; ++kc) {
      short8 af[4], bfr[4];
#pragma unroll
      for (int rt = 0; rt < 4; ++rt)
        af[rt] = *(const short8*)(A + (size_t)(n0 + rt * 16 + ml) * D_IN + kc * 32 + q * 8);
#pragma unroll
      for (int cl = 0; cl < 4; ++cl)
        bfr[cl] = *(const short8*)(B + ((size_t)((w * 4 + cl) * 2 + kc) * 64 + lane) * 8);
#pragma unroll
      for (int rt = 0; rt < 4; ++rt)
#pragma unroll
        for (int cl = 0; cl < 4; ++cl)
          acc[rt][cl] = __builtin_amdgcn_mfma_f32_16x16x32_bf16(af[rt], bfr[cl], acc[rt][cl], 0, 0, 0);
    }
  }

#pragma unroll
  for (int cl = 0; cl < 4; ++cl) {
    const int col = w * 64 + cl * 16 + ml;
    const float bias = bl[col];
#pragma unroll
    for (int rt = 0; rt < 4; ++rt) {
#pragma unroll
      for (int i = 0; i < 4; ++i) {
        const int row = n0 + rt * 16 + q * 4 + i;
        drug[(size_t)row * HID + col] =
            (unsigned short)bf16rne(fmaxf(acc[rt][cl][i] + bias, 0.f));
      }
    }
  }
}

// ---------------------------------------------------------------------------
// k_pool: blocks [0,1024) pool one graph each (8-deep ILP column sum of drug,
// write bf16 mean into comb[g][0:256]); blocks [1024,1280) reduce prot4
// partials + bp into comb[g][256:512]. comb is the bf16 A-matrix for k_tail.
// ---------------------------------------------------------------------------
__device__ inline int lb_dev(const int* __restrict__ a, int v) {
  int lo = 0, hi = N_NODES;
  while (lo < hi) { int m = (lo + hi) >> 1; if (a[m] < v) lo = m + 1; else hi = m; }
  return lo;
}

__global__ __launch_bounds__(256) void k_pool(
    const unsigned short* __restrict__ drug, const int* __restrict__ batch,
    const float* __restrict__ prot4, const float* __restrict__ bp,
    unsigned short* __restrict__ comb) {
  const int t = threadIdx.x;
  if (blockIdx.x < N_GRAPHS) {
    const int g = blockIdx.x;
    const int lo = lb_dev(batch, g);
    const int hi = lb_dev(batch, g + 1);
    float s0 = 0.f, s1 = 0.f, s2 = 0.f, s3 = 0.f;
    float s4 = 0.f, s5 = 0.f, s6 = 0.f, s7 = 0.f;
    int r = lo;
    for (; r + 8 <= hi; r += 8) {
      s0 += __uint_as_float((unsigned)drug[(size_t)(r + 0) * HID + t] << 16);
      s1 += __uint_as_float((unsigned)drug[(size_t)(r + 1) * HID + t] << 16);
      s2 += __uint_as_float((unsigned)drug[(size_t)(r + 2) * HID + t] << 16);
      s3 += __uint_as_float((unsigned)drug[(size_t)(r + 3) * HID + t] << 16);
      s4 += __uint_as_float((unsigned)drug[(size_t)(r + 4) * HID + t] << 16);
      s5 += __uint_as_float((unsigned)drug[(size_t)(r + 5) * HID + t] << 16);
      s6 += __uint_as_float((unsigned)drug[(size_t)(r + 6) * HID + t] << 16);
      s7 += __uint_as_float((unsigned)drug[(size_t)(r + 7) * HID + t] << 16);
    }
    for (; r < hi; ++r)
      s0 += __uint_as_float((unsigned)drug[(size_t)r * HID + t] << 16);
    float inv = 1.0f / (float)max(hi - lo, 1);
    float m = (((s0 + s1) + (s2 + s3)) + ((s4 + s5) + (s6 + s7))) * inv;
    comb[(size_t)g * 512 + t] = (unsigned short)bf16rne(m);
    return;
  }
  const int pb = blockIdx.x - N_GRAPHS;   // 0..255, 4 graphs each
#pragma unroll
  for (int g = 0; g < 4; ++g) {
    const int gg = pb * 4 + g;
    size_t idx = (size_t)gg * HID + t;
    float pr = prot4[idx] + prot4[(size_t)N_GRAPHS * HID + idx]
             + prot4[2 * (size_t)N_GRAPHS * HID + idx]
             + prot4[3 * (size_t)N_GRAPHS * HID + idx];
    comb[(size_t)gg * 512 + HID + t] = (unsigned short)bf16rne(pr + bp[t]);
  }
}

// ---------------------------------------------------------------------------
// k_tail: MFMA interaction comb[1024x512] @ Wi_pk[512x256], then fused
// bias+relu+(*Wo)+column-reduce head. 64 blocks x 16 graphs.
// ---------------------------------------------------------------------------
__global__ __launch_bounds__(256) void k_tail(
    const bf16* __restrict__ comb, const bf16* __restrict__ Wi_pk,
    const float* __restrict__ bi, const float* __restrict__ Wo,
    const float* __restrict__ bo, float* __restrict__ out) {
  __shared__ float sRed[16 * 4];
  const int t = threadIdx.x, w = t >> 6, lane = t & 63;
  const int ml = lane & 15, q = lane >> 4;
  const int g0 = blockIdx.x * 16;
  f32x4 acc[4];
#pragma unroll
  for (int c = 0; c < 4; ++c) acc[c] = (f32x4){0.f, 0.f, 0.f, 0.f};
  for (int kc = 0; kc < 16; ++kc) {
    short8 a = *(const short8*)(comb + (size_t)(g0 + ml) * 512 + kc * 32 + q * 8);
#pragma unroll
    for (int cl = 0; cl < 4; ++cl) {
      short8 bb = *(const short8*)(Wi_pk + ((size_t)((w * 4 + cl) * 16 + kc) * 64 + lane) * 8);
      acc[cl] = __builtin_amdgcn_mfma_f32_16x16x32_bf16(a, bb, acc[cl], 0, 0, 0);
    }
  }
  // epilogue: inter = relu(acc + bi); partial = inter * Wo; reduce over cols
  float bic[4], woc[4];
#pragma unroll
  for (int cl = 0; cl < 4; ++cl) {
    const int col = w * 64 + cl * 16 + ml;
    bic[cl] = bi[col];
    woc[cl] = Wo[col];
  }
#pragma unroll
  for (int i = 0; i < 4; ++i) {
    float s = 0.f;
#pragma unroll
    for (int cl = 0; cl < 4; ++cl)
      s += fmaxf(acc[cl][i] + bic[cl], 0.f) * woc[cl];
    // reduce over the 16 ml lanes (stays within same q group)
    s += __shfl_xor(s, 1); s += __shfl_xor(s, 2);
    s += __shfl_xor(s, 4); s += __shfl_xor(s, 8);
    if (ml == 0) sRed[(q * 4 + i) * 4 + w] = s;
  }
  __syncthreads();
  if (t < 16)
    out[g0 + t] = sRed[t * 4 + 0] + sRed[t * 4 + 1] + sRed[t * 4 + 2]
                + sRed[t * 4 + 3] + bo[0];
}

extern "C" void kernel_launch(void* const* d_in, const int* in_sizes, int n_in,
                              void* d_out, int out_size, void* d_ws, size_t ws_size,
                              hipStream_t stream) {
  const float* x     = (const float*)d_in[0];
  const float* pe    = (const float*)d_in[1];
  const float* Wl    = (const float*)d_in[2];
  const float* bl    = (const float*)d_in[3];
  const float* Wr    = (const float*)d_in[4];
  const float* Wp    = (const float*)d_in[5];
  const float* bp    = (const float*)d_in[6];
  const float* Wi    = (const float*)d_in[7];
  const float* bi    = (const float*)d_in[8];
  const float* Wo    = (const float*)d_in[9];
  const float* bo    = (const float*)d_in[10];
  const int*   ei    = (const int*)d_in[11];
  const int*   batch = (const int*)d_in[12];
  float* out = (float*)d_out;

  char* p = (char*)d_ws;
  auto alloc = [&](size_t bytes) {
    char* r = p;
    p += (bytes + 255) & ~(size_t)255;
    return r;
  };
  int*      bcnt  = (int*)alloc(NB * 4);
  size_t zbytes = (size_t)(p - (char*)d_ws);     // only bcnt needs zeroing
  unsigned* bped  = (unsigned*)alloc((size_t)NB * BCAP * 4);
  bf16*  xbf    = (bf16*)alloc((size_t)N_PAD * D_IN * 2);
  bf16*  aggrbf = (bf16*)alloc((size_t)N_PAD * D_IN * 2);
  bf16*  pebf   = (bf16*)alloc((size_t)N_GRAPHS * D_PROT * 2);
  bf16*  Wl_pk  = (bf16*)alloc((size_t)D_IN * HID * 2);
  bf16*  Wr_pk  = (bf16*)alloc((size_t)D_IN * HID * 2);
  bf16*  Wp_pk  = (bf16*)alloc((size_t)D_PROT * HID * 2);
  bf16*  Wi_pk  = (bf16*)alloc((size_t)2 * HID * HID * 2);
  float* prot4  = (float*)alloc((size_t)4 * N_GRAPHS * HID * 4);
  unsigned short* drug = (unsigned short*)alloc((size_t)N_PAD * HID * 2);
  unsigned short* comb = (unsigned short*)alloc((size_t)N_GRAPHS * 2 * HID * 2);

  (void)hipMemsetAsync(d_ws, 0, zbytes, stream);

  k_front<<<BBLK + PREP_WI, 256, 0, stream>>>(
      x, pe, Wl, Wr, Wp, Wi, ei,
      (uint2*)xbf, (uint2*)pebf, Wl_pk, Wr_pk, Wp_pk, Wi_pk, bcnt, bped);
  k_mid<<<NB + 256, 256, 0, stream>>>(
      (const uint2*)xbf, bped, bcnt, (uint2*)aggrbf, pebf, Wp_pk, prot4);
  k_mlp<<<N_PAD / 64, 256, 0, stream>>>(aggrbf, xbf, Wl_pk, Wr_pk, bl, drug);
  k_pool<<<N_GRAPHS + 256, 256, 0, stream>>>(drug, batch, prot4, bp, comb);
  k_tail<<<N_GRAPHS / 16, 256, 0, stream>>>((const bf16*)comb, Wi_pk, bi, Wo, bo, out);
}